// Round 10
// baseline (83.578 us; speedup 1.0000x reference)
//
#include <hip/hip_runtime.h>

typedef __attribute__((ext_vector_type(8))) __bf16 bf16x8;
typedef __attribute__((ext_vector_type(4))) __bf16 bf16x4;
typedef __attribute__((ext_vector_type(4))) float f32x4;

// barrier WITHOUT vmcnt drain: LDS ops must land, global loads stay in flight
#define LGKM_BAR() do { asm volatile("s_waitcnt lgkmcnt(0)" ::: "memory"); \
                        __builtin_amdgcn_s_barrier(); } while (0)

namespace {
constexpr int N_ = 64, C_ = 512, P_ = 900, K_ = 64;
constexpr int PP = 960;                               // padded P for at
constexpr size_t TOT_X = (size_t)N_ * C_ * P_;        // 117,964,800 floats
constexpr size_t AT_BYTES = (size_t)N_ * K_ * PP * 2;         // bf16 a' [n][k][960]
constexpr size_t ASUM_OFF = AT_BYTES;                         // f32 [n][k]
constexpr size_t WBR_OFF  = ASUM_OFF + (size_t)N_ * K_ * 4;   // bf16 wbr [c/8][k][c%8]
}

// --- prep: wbr[oct][k][j] = bf16(w[k][oct*8+j]) (A-frag-ready layout); zero asum.
__global__ __launch_bounds__(256) void k_prep_w(const float* __restrict__ w,
                                                __bf16* __restrict__ wbr,
                                                float* __restrict__ asum) {
  const int T = blockIdx.x * 256 + threadIdx.x;      // 0..4095
  const int k = T >> 6, oct = T & 63;
  const float4 a = *reinterpret_cast<const float4*>(w + (size_t)k * C_ + oct * 8);
  const float4 b = *reinterpret_cast<const float4*>(w + (size_t)k * C_ + oct * 8 + 4);
  bf16x8 o = { (__bf16)a.x, (__bf16)a.y, (__bf16)a.z, (__bf16)a.w,
               (__bf16)b.x, (__bf16)b.y, (__bf16)b.z, (__bf16)b.w };
  *reinterpret_cast<bf16x8*>(wbr + ((size_t)oct * K_ + k) * 8) = o;
  asum[T] = 0.f;
}

// --- phase 1, phase2-style: coalesced float4 staging -> padded [c][66] bf16 tile,
//     conflict-free u16 fragment reads, dbuf + lgkm-only barriers, W in LDS.
//     Block 256 thr / 4 waves; wave w owns p = p0 + w*16 + l15, all 64 k.
__global__ __launch_bounds__(256) void k_phase1(const float* __restrict__ x,
                                                const __bf16* __restrict__ wbr,
                                                __bf16* __restrict__ at,
                                                float* __restrict__ asum) {
  __shared__ bf16x8 Wl[4096];        // 64 KB: [oct][k] -> one b128 = A-frag slice
  __shared__ __bf16 Xl[2][32][66];   // staged x^T tile, padded rows (132 B)
  __shared__ float ssq_l[64];
  const int n   = blockIdx.y;
  const int p0  = blockIdx.x * 64;
  const int tid = threadIdx.x;
  const int w   = tid >> 6, l = tid & 63;
  const int l15 = l & 15,  lh = l >> 4;
  const int p   = p0 + w * 16 + l15;                // this lane's p (D col)

  // one-time stage wbr -> LDS
  bf16x8 tmp[16];
  #pragma unroll
  for (int it = 0; it < 16; ++it)
    tmp[it] = *reinterpret_cast<const bf16x8*>(wbr + (size_t)(it * 256 + tid) * 8);
  #pragma unroll
  for (int it = 0; it < 16; ++it)
    Wl[it * 256 + tid] = tmp[it];
  if (tid < 64) ssq_l[tid] = 0.f;

  // staging map: thread covers c-rows {sc, sc+16} (stepped), p-quad pq..pq+3
  const int sc = tid >> 4, pq = (tid & 15) * 4;
  const bool pvalid = (p0 + pq) < P_;               // float4 fully in-bounds iff start<900
  const size_t xs = (size_t)n * C_ * P_ + p0 + pq;
  float f[8];
  float sq[4] = {0.f, 0.f, 0.f, 0.f};

  auto LOAD = [&](int s) {
    if (pvalid) {
      const float4 v0 = *reinterpret_cast<const float4*>(x + xs + (size_t)(s * 32 + sc) * P_);
      const float4 v1 = *reinterpret_cast<const float4*>(x + xs + (size_t)(s * 32 + sc + 16) * P_);
      f[0]=v0.x; f[1]=v0.y; f[2]=v0.z; f[3]=v0.w;
      f[4]=v1.x; f[5]=v1.y; f[6]=v1.z; f[7]=v1.w;
    } else {
      #pragma unroll
      for (int j = 0; j < 8; ++j) f[j] = 0.f;
    }
  };
  auto STORE = [&](int b) {
    #pragma unroll
    for (int j = 0; j < 8; ++j) sq[j & 3] = fmaf(f[j], f[j], sq[j & 3]);
    bf16x4 a0 = { (__bf16)f[0], (__bf16)f[1], (__bf16)f[2], (__bf16)f[3] };
    bf16x4 a1 = { (__bf16)f[4], (__bf16)f[5], (__bf16)f[6], (__bf16)f[7] };
    *reinterpret_cast<bf16x4*>(&Xl[b][sc][pq])      = a0;
    *reinterpret_cast<bf16x4*>(&Xl[b][sc + 16][pq]) = a1;
  };

  LOAD(0); STORE(0);
  LGKM_BAR();                         // also covers Wl stores

  f32x4 acc[4] = {};                  // m: k = 16m + lh*4 + r
  #pragma unroll
  for (int s = 0; s < 16; ++s) {
    if (s < 15) LOAD(s + 1);
    // B-frag: 8 scalar reads, conflict-free (33-dword row stride, lane-pairs share dwords)
    bf16x8 b;
    #pragma unroll
    for (int j = 0; j < 8; ++j) b[j] = Xl[s & 1][lh * 8 + j][w * 16 + l15];
    #pragma unroll
    for (int m = 0; m < 4; ++m) {
      bf16x8 a = Wl[(s * 4 + lh) * 64 + 16 * m + l15];
      acc[m] = __builtin_amdgcn_mfma_f32_16x16x32_bf16(a, b, acc[m], 0, 0, 0);
    }
    if (s < 15) { STORE((s + 1) & 1); LGKM_BAR(); }
  }

  // ssq: staging-thread partials -> LDS atomics -> full per-p sums
  #pragma unroll
  for (int i = 0; i < 4; ++i) atomicAdd(&ssq_l[pq + i], sq[i]);
  __syncthreads();

  const float invn = 1.f / fmaxf(sqrtf(ssq_l[w * 16 + l15]), 1e-12f);
  const bool  valid = p < P_;

  float ps = 0.f;
  #pragma unroll
  for (int m = 0; m < 4; ++m)
    #pragma unroll
    for (int r = 0; r < 4; ++r) {
      acc[m][r] = __expf(acc[m][r] * invn);   // maxless: |logit| <= ~0.5
      ps += acc[m][r];
    }
  ps += __shfl_xor(ps, 16, 64);
  ps += __shfl_xor(ps, 32, 64);
  const float invs = 1.f / ps;
  const float sc2  = invs * invn;

  #pragma unroll
  for (int m = 0; m < 4; ++m)
    #pragma unroll
    for (int r = 0; r < 4; ++r) {
      const int k = 16 * m + lh * 4 + r;
      at[((size_t)n * K_ + k) * PP + p] =
          valid ? (__bf16)(acc[m][r] * sc2) : (__bf16)0.f;
    }
  #pragma unroll
  for (int m = 0; m < 4; ++m)
    #pragma unroll
    for (int r = 0; r < 4; ++r) {
      float v = valid ? acc[m][r] * invs : 0.f;
      v += __shfl_xor(v, 1, 64); v += __shfl_xor(v, 2, 64);
      v += __shfl_xor(v, 4, 64); v += __shfl_xor(v, 8, 64);
      if (l15 == 0)
        unsafeAtomicAdd(asum + n * K_ + 16 * m + lh * 4 + r, v);
    }
}

// --- phase 2 (unchanged): vlad[k][c] = sum_p a'[k][p]*x[c][p] - asum[k]*cent[k][c]
__global__ __launch_bounds__(256) void k_phase2(const float* __restrict__ x,
                                                const __bf16* __restrict__ at,
                                                const float* __restrict__ asum,
                                                const float* __restrict__ cent,
                                                float* __restrict__ out) {
  __shared__ __bf16 Al[2][64][40];   // [buf][k][p32+pad]
  __shared__ __bf16 Xl[2][64][40];   // [buf][c][p32+pad]
  const int n   = blockIdx.y;
  const int c0  = blockIdx.x * 64;
  const int tid = threadIdx.x;
  const int w   = tid >> 6, l = tid & 63;
  const int l15 = l & 15,  lh = l >> 4;

  const int ak  = tid >> 2, ach = tid & 3;      // A staging: k, p-octet
  const int xc  = tid >> 3, xch = tid & 7;      // X staging (x2): c, p-quad
  const size_t abase  = ((size_t)n * K_ + ak) * PP + ach * 8;
  const size_t xbase0 = ((size_t)n * C_ + c0 + xc) * P_ + xch * 4;
  const size_t xbase1 = ((size_t)n * C_ + c0 + xc + 32) * P_ + xch * 4;

  f32x4 acc[4] = {};                 // frag m: k=16m+lh*4+r, c=c0+16w+l15
  bf16x8 na; float4 v0, v1;

  auto LOAD = [&](int s) {
    na = *reinterpret_cast<const bf16x8*>(at + abase + s * 32);
    size_t o0 = xbase0 + s * 32; if (o0 > TOT_X - 4) o0 = TOT_X - 4;
    size_t o1 = xbase1 + s * 32; if (o1 > TOT_X - 4) o1 = TOT_X - 4;
    v0 = *reinterpret_cast<const float4*>(x + o0);
    v1 = *reinterpret_cast<const float4*>(x + o1);
  };
  auto STORE = [&](int b) {
    *reinterpret_cast<bf16x8*>(&Al[b][ak][ach * 8]) = na;
    bf16x4 p0 = { (__bf16)v0.x, (__bf16)v0.y, (__bf16)v0.z, (__bf16)v0.w };
    bf16x4 p1 = { (__bf16)v1.x, (__bf16)v1.y, (__bf16)v1.z, (__bf16)v1.w };
    *reinterpret_cast<bf16x4*>(&Xl[b][xc][xch * 4])      = p0;
    *reinterpret_cast<bf16x4*>(&Xl[b][xc + 32][xch * 4]) = p1;
  };

  LOAD(0); STORE(0);
  LGKM_BAR();

  #pragma unroll 2
  for (int s = 0; s < 29; ++s) {     // K-dim p: 29 steps of 32 (at pad = 0)
    if (s < 28) LOAD(s + 1);
    bf16x8 b = *reinterpret_cast<const bf16x8*>(&Xl[s & 1][16 * w + l15][lh * 8]);
    #pragma unroll
    for (int m = 0; m < 4; ++m) {
      bf16x8 a = *reinterpret_cast<const bf16x8*>(&Al[s & 1][16 * m + l15][lh * 8]);
      acc[m] = __builtin_amdgcn_mfma_f32_16x16x32_bf16(a, b, acc[m], 0, 0, 0);
    }
    if (s < 28) STORE((s + 1) & 1);
    LGKM_BAR();
  }

  const int c = c0 + 16 * w + l15;
  #pragma unroll
  for (int m = 0; m < 4; ++m) {
    #pragma unroll
    for (int r = 0; r < 4; ++r) {
      const int k = 16 * m + lh * 4 + r;
      out[((size_t)n * K_ + k) * C_ + c] =
          acc[m][r] - asum[n * K_ + k] * cent[(size_t)k * C_ + c];
    }
  }
}

extern "C" void kernel_launch(void* const* d_in, const int* in_sizes, int n_in,
                              void* d_out, int out_size, void* d_ws, size_t ws_size,
                              hipStream_t stream) {
  const float* x    = (const float*)d_in[0];
  const float* w    = (const float*)d_in[1];
  const float* cent = (const float*)d_in[2];
  float* out = (float*)d_out;
  char* wsb  = (char*)d_ws;
  __bf16* at   = (__bf16*)wsb;
  float*  asum = (float*)(wsb + ASUM_OFF);
  __bf16* wbr  = (__bf16*)(wsb + WBR_OFF);

  k_prep_w<<<dim3(16), dim3(256), 0, stream>>>(w, wbr, asum);
  k_phase1<<<dim3(15, 64), dim3(256), 0, stream>>>(x, wbr, at, asum);
  k_phase2<<<dim3(8, 64), dim3(256), 0, stream>>>(x, at, asum, cent, out);
}